// Round 7
// baseline (176.303 us; speedup 1.0000x reference)
//
#include <hip/hip_runtime.h>
#include <hip/hip_bf16.h>
#include <hip/hip_cooperative_groups.h>

namespace cg = cooperative_groups;

// AdditiveAttention: B=8, Q=128, V=512, H=512.
// out = [context (B*Q*H) | weights (B*Q*V)] fp32.
// ws: qp [1024*512] f32 @0, vp [4096*512] f32 @2MB (10MB).
// bc dropped (softmax shift-invariant); sum_h wc[h] const also cancels.
// Score math (verified R1-R5): tanh(y)=1-2r, r=1/(2^(C*y)+1), C=2*log2(e);
//   softmax arg = -C * sum_h wc[h]*r (consts dropped), min-based softmax;
//   shared-exp: e1 = e0 * f_h, f_h = 2^(C*(q1-q0)_h).
// R7: R6's coop fusion, made launch-safe. R6 failed silently: phase A's
//   64-VGPR prefetch arrays + 16 AGPR busted the 128-reg budget of
//   launch_bounds(512,4) -> occupancy 1 blk/CU -> coop max 256 < 512 ->
//   hipErrorCooperativeLaunchTooLarge (unchecked). Fixes: (a) register-lean
//   phase A (no prefetch array, unroll 1); (b) host-side occupancy query
//   picks coop vs identical-math two-kernel fallback (deterministic, same
//   work every call); (c) coop return code checked.

#define C_SCALE 2.8853900817779268f

typedef __attribute__((ext_vector_type(8))) short short8;
typedef __attribute__((ext_vector_type(4))) float f32x4;

__device__ __forceinline__ float fexp2(float x) { return __builtin_amdgcn_exp2f(x); }
__device__ __forceinline__ float frcp(float x)  { return __builtin_amdgcn_rcpf(x); }
__device__ __forceinline__ float asfloat(unsigned u) { return __builtin_bit_cast(float, u); }
__device__ __forceinline__ unsigned asuint(float f) { return __builtin_bit_cast(unsigned, f); }

// truncation split: hi = x[31:16] as bf16, lo = (x - hi) as bf16
__device__ __forceinline__ void split8(float4 u, float4 v, short8& hi, short8& lo) {
  unsigned a[8] = {asuint(u.x), asuint(u.y), asuint(u.z), asuint(u.w),
                   asuint(v.x), asuint(v.y), asuint(v.z), asuint(v.w)};
  unsigned r[8];
#pragma unroll
  for (int j = 0; j < 8; ++j)
    r[j] = asuint(asfloat(a[j]) - asfloat(a[j] & 0xFFFF0000u));
  uint4 h, l;
  h.x = __builtin_amdgcn_perm(a[1], a[0], 0x07060302u);
  h.y = __builtin_amdgcn_perm(a[3], a[2], 0x07060302u);
  h.z = __builtin_amdgcn_perm(a[5], a[4], 0x07060302u);
  h.w = __builtin_amdgcn_perm(a[7], a[6], 0x07060302u);
  l.x = __builtin_amdgcn_perm(r[1], r[0], 0x07060302u);
  l.y = __builtin_amdgcn_perm(r[3], r[2], 0x07060302u);
  l.z = __builtin_amdgcn_perm(r[5], r[4], 0x07060302u);
  l.w = __builtin_amdgcn_perm(r[7], r[6], 0x07060302u);
  hi = __builtin_bit_cast(short8, h);
  lo = __builtin_bit_cast(short8, l);
}

struct SM {
  int   idxs[512];
  float wls[2][512];     // raw acc per (q, slot); 3.4e38 = invalid
  float wls2[512][2];    // final weights per slot (q0,q1)
  float qps[512];        // C * qp[row q0]
  float fls[512];        // f_h = 2^(C*(q1-q0)_h)
  float wcs[512];
  int   cnt8[8];
};

// ---- setup: LDS init, wc stage, out_w zero, mask compaction; returns cnt ----
__device__ __forceinline__ int setup_phase(SM& sm, int t, int lane, int w,
    int b, int rowbase, const int* __restrict__ mask,
    const float* __restrict__ wc, float* __restrict__ out_w)
{
  ((float*)sm.wls)[t]        = 3.4e38f;
  ((float*)sm.wls)[t + 512]  = 3.4e38f;
  ((float*)sm.wls2)[t]       = 0.f;
  ((float*)sm.wls2)[t + 512] = 0.f;
  sm.idxs[t] = 0;
  if (t < 128) ((float4*)sm.wcs)[t] = ((const float4*)wc)[t];
  if (t < 256) {
    float4 z = {0.f, 0.f, 0.f, 0.f};
    ((float4*)(out_w + (size_t)rowbase * 512))[t] = z;
  }
  const int mv = mask[b * 512 + t];
  const unsigned long long bal = __ballot(mv != 0);
  if (lane == 0) sm.cnt8[w] = __popcll(bal);
  __syncthreads();
  int cnt = 0, offw = 0;
#pragma unroll
  for (int j = 0; j < 8; ++j) { if (j == w) offw = cnt; cnt += sm.cnt8[j]; }
  if (mv) {
    int rank = __popcll(bal & ((1ull << lane) - 1ull));
    sm.idxs[offw + rank] = t;
  }
  __syncthreads();
  return cnt;
}

// ---- phase A: per-wave 32x32 split-bf16 MFMA gemm job ----------------------
// Per XCD-key r = bx&7: wave-slot i = (bx>>3)*8 + w in [0,512):
//   i < 256: v-job m-tile (r*16 + i>>4), n-tile i&15   (vp rows of batch r)
//   i < 320: q-job m-tile (r*4 + (i-256)>>4), n-tile (i-256)&15
__device__ __forceinline__ void gemm_phase(int bx, int t,
    const float* __restrict__ query, const float* __restrict__ values,
    const float* __restrict__ Wq, const float* __restrict__ bq,
    const float* __restrict__ Wv, const float* __restrict__ bv,
    float* __restrict__ qp, float* __restrict__ vp)
{
  const int lane = t & 63, w = t >> 6, b = bx & 7;
  const int i = ((bx >> 3) << 3) + w;
  if (i >= 320) return;

  int m0; const float *A, *W, *bias; float* outp;
  if (i < 256) {
    m0 = (b * 16 + (i >> 4)) << 5;  A = values; W = Wv; bias = bv; outp = vp;
  } else {
    const int ii = i - 256;
    m0 = (b * 4 + (ii >> 4)) << 5;  A = query;  W = Wq; bias = bq; outp = qp;
  }
  const int n0 = (i & 15) << 5;
  const int frow = lane & 15, fq8 = (lane >> 4) << 3, fquad = lane >> 4;

  const float* ap0 = A + (size_t)(m0 + frow) * 512 + fq8;
  const float* ap1 = ap0 + (size_t)16 * 512;
  const float* wp0 = W + (size_t)(n0 + frow) * 512 + fq8;
  const float* wp1 = wp0 + (size_t)16 * 512;

  f32x4 acc[2][2] = {};
#pragma unroll 1
  for (int kc = 0; kc < 512; kc += 32) {
    float4 c0 = *(const float4*)(ap0 + kc);
    float4 c1 = *(const float4*)(ap0 + kc + 4);
    float4 c2 = *(const float4*)(ap1 + kc);
    float4 c3 = *(const float4*)(ap1 + kc + 4);
    float4 c4 = *(const float4*)(wp0 + kc);
    float4 c5 = *(const float4*)(wp0 + kc + 4);
    float4 c6 = *(const float4*)(wp1 + kc);
    float4 c7 = *(const float4*)(wp1 + kc + 4);
    short8 ahi[2], alo[2], whi[2], wlo[2];
    split8(c0, c1, ahi[0], alo[0]);
    split8(c2, c3, ahi[1], alo[1]);
    split8(c4, c5, whi[0], wlo[0]);
    split8(c6, c7, whi[1], wlo[1]);
#pragma unroll
    for (int mt = 0; mt < 2; ++mt)
#pragma unroll
      for (int nt = 0; nt < 2; ++nt) {
        acc[mt][nt] = __builtin_amdgcn_mfma_f32_16x16x32_bf16(
            alo[mt], whi[nt], acc[mt][nt], 0, 0, 0);
        acc[mt][nt] = __builtin_amdgcn_mfma_f32_16x16x32_bf16(
            ahi[mt], wlo[nt], acc[mt][nt], 0, 0, 0);
        acc[mt][nt] = __builtin_amdgcn_mfma_f32_16x16x32_bf16(
            ahi[mt], whi[nt], acc[mt][nt], 0, 0, 0);
      }
  }

  // epilogue: C/D layout col = lane&15, row = (lane>>4)*4 + reg (R3-verified)
#pragma unroll
  for (int nt = 0; nt < 2; ++nt) {
    const int nn = n0 + nt * 16 + frow;
    const float bn = bias[nn];
#pragma unroll
    for (int mt = 0; mt < 2; ++mt) {
      float vreg[4] = {acc[mt][nt].x, acc[mt][nt].y, acc[mt][nt].z, acc[mt][nt].w};
#pragma unroll
      for (int rr = 0; rr < 4; ++rr) {
        const int m = m0 + mt * 16 + fquad * 4 + rr;
        outp[(size_t)m * 512 + nn] = vreg[rr] + bn;
      }
    }
  }
}

// ---- attn tail: score (slot-outer), softmax, context -----------------------
__device__ __forceinline__ void attn_tail(SM& sm, int t, int lane, int w,
    int b, int rowbase, int cnt,
    const float* __restrict__ qp, const float* __restrict__ vp,
    const float* __restrict__ values,
    float* __restrict__ out_ctx, float* __restrict__ out_w)
{
  { // stage q0 (prescaled) and f_h
    const float q0 = qp[(size_t)rowbase * 512 + t];
    const float q1 = qp[(size_t)(rowbase + 1) * 512 + t];
    sm.qps[t] = C_SCALE * q0;
    sm.fls[t] = fexp2(C_SCALE * (q1 - q0));
  }
  __syncthreads();

  // score: wave w owns slots [w*4*NSTEP, ...); lane = (g = lane>>4, hquad)
  const int NSTEP = (cnt + 31) >> 5;       // 1..16
  const int sbase = w * (NSTEP << 2);
  const int g  = lane >> 4;
  const int c4 = (lane & 15) << 2;
  const float* vpb = vp + (size_t)b * 512 * 512;

  for (int i = 0; i < NSTEP; ++i) {
    const int s = sbase + (i << 2) + g;
    const int row = sm.idxs[s];
    const float* vr = vpb + (size_t)row * 512 + c4;
    float4 v8[8];
#pragma unroll
    for (int j = 0; j < 8; ++j) v8[j] = *(const float4*)(vr + (j << 6));
    float s0 = 0.f, s1 = 0.f;
#pragma unroll
    for (int j = 0; j < 8; ++j) {
      const int hoff = (j << 6) + c4;
      float4 q4 = *(const float4*)&sm.qps[hoff];
      float4 w4 = *(const float4*)&sm.wcs[hoff];
      float4 f4 = *(const float4*)&sm.fls[hoff];
      float qv[4] = {q4.x, q4.y, q4.z, q4.w};
      float wv[4] = {w4.x, w4.y, w4.z, w4.w};
      float fv[4] = {f4.x, f4.y, f4.z, f4.w};
      float vv[4] = {v8[j].x, v8[j].y, v8[j].z, v8[j].w};
#pragma unroll
      for (int k = 0; k < 4; ++k) {
        float e0 = fexp2(__builtin_fmaf(C_SCALE, vv[k], qv[k]));
        float r0 = frcp(e0 + 1.0f);
        s0 = __builtin_fmaf(wv[k], r0, s0);
        float e1 = e0 * fv[k];               // shared exp
        float r1 = frcp(e1 + 1.0f);
        s1 = __builtin_fmaf(wv[k], r1, s1);
      }
    }
#pragma unroll
    for (int off = 1; off < 16; off <<= 1) { // reduce 16 lanes sharing g
      s0 += __shfl_xor(s0, off, 64);
      s1 += __shfl_xor(s1, off, 64);
    }
    if ((lane & 15) == 0 && s < cnt) { sm.wls[0][s] = s0; sm.wls[1][s] = s1; }
  }
  __syncthreads();

  // softmax (min-based; waves 0-3 -> q0, 4-7 -> q1; waves 0/4 write)
  {
    const int mq = (w >= 4) ? 1 : 0;
    const float* sc = sm.wls[mq];
    float4 u0 = ((const float4*)sc)[lane * 2];
    float4 u1 = ((const float4*)sc)[lane * 2 + 1];
    float s8[8] = {u0.x, u0.y, u0.z, u0.w, u1.x, u1.y, u1.z, u1.w};
    float m = s8[0];
#pragma unroll
    for (int k = 1; k < 8; ++k) m = fminf(m, s8[k]);
#pragma unroll
    for (int off = 1; off < 64; off <<= 1) m = fminf(m, __shfl_xor(m, off, 64));
    float e[8], S = 0.f;
#pragma unroll
    for (int k = 0; k < 8; ++k) { e[k] = fexp2(C_SCALE * (m - s8[k])); S += e[k]; }
#pragma unroll
    for (int off = 1; off < 64; off <<= 1) S += __shfl_xor(S, off, 64);
    const float rinv = frcp(S);
    if (w == 0 || w == 4) {
      float* owq = out_w + (size_t)(rowbase + mq) * 512;
#pragma unroll
      for (int k = 0; k < 8; ++k) {
        const int s = lane * 8 + k;
        const float wgt = e[k] * rinv;       // invalid slots -> 0
        sm.wls2[s][mq] = wgt;
        if (s < cnt) owq[sm.idxs[s]] = wgt;
      }
    }
  }
  __syncthreads();

  // context: wave w owns h-window [w*64, w*64+64)
  const int NC = (cnt + 3) >> 2;
  const int hbase = w * 64 + c4;
  const float* vb = values + (size_t)b * 512 * 512;
  float c0[4] = {0.f, 0.f, 0.f, 0.f}, c1[4] = {0.f, 0.f, 0.f, 0.f};
#pragma unroll 4
  for (int i = 0; i < NC; ++i) {
    const int s = (i << 2) + g;
    const int row = sm.idxs[s];
    const float2 wg = *(const float2*)&sm.wls2[s][0];  // padded slots: 0
    const float4 v4 = *(const float4*)(vb + (size_t)row * 512 + hbase);
    float vv[4] = {v4.x, v4.y, v4.z, v4.w};
#pragma unroll
    for (int k = 0; k < 4; ++k) {
      c0[k] = __builtin_fmaf(wg.x, vv[k], c0[k]);
      c1[k] = __builtin_fmaf(wg.y, vv[k], c1[k]);
    }
  }
#pragma unroll
  for (int k = 0; k < 4; ++k) {                        // reduce over g
    c0[k] += __shfl_xor(c0[k], 16, 64); c0[k] += __shfl_xor(c0[k], 32, 64);
    c1[k] += __shfl_xor(c1[k], 16, 64); c1[k] += __shfl_xor(c1[k], 32, 64);
  }
  if (lane < 16) {
    float4 o0 = {c0[0], c0[1], c0[2], c0[3]};
    float4 o1 = {c1[0], c1[1], c1[2], c1[3]};
    *(float4*)(out_ctx + (size_t)rowbase * 512 + w * 64 + lane * 4)       = o0;
    *(float4*)(out_ctx + (size_t)(rowbase + 1) * 512 + w * 64 + lane * 4) = o1;
  }
}

// ---- kernels ---------------------------------------------------------------
__global__ __launch_bounds__(512, 4) void fused_all(
    const float* __restrict__ query, const float* __restrict__ values,
    const int* __restrict__ mask,
    const float* __restrict__ Wq, const float* __restrict__ bq,
    const float* __restrict__ Wv, const float* __restrict__ bv,
    const float* __restrict__ wc,
    float* __restrict__ qp, float* __restrict__ vp,
    float* __restrict__ out_ctx, float* __restrict__ out_w)
{
  __shared__ SM sm;
  const int t = threadIdx.x, lane = t & 63, w = t >> 6;
  const int b = blockIdx.x & 7, qg = blockIdx.x >> 3;
  const int rowbase = b * 128 + qg * 2;
  const int cnt = setup_phase(sm, t, lane, w, b, rowbase, mask, wc, out_w);
  gemm_phase(blockIdx.x, t, query, values, Wq, bq, Wv, bv, qp, vp);
  cg::this_grid().sync();
  attn_tail(sm, t, lane, w, b, rowbase, cnt, qp, vp, values, out_ctx, out_w);
}

__global__ __launch_bounds__(512, 4) void k_gemm(
    const float* __restrict__ query, const float* __restrict__ values,
    const float* __restrict__ Wq, const float* __restrict__ bq,
    const float* __restrict__ Wv, const float* __restrict__ bv,
    float* __restrict__ qp, float* __restrict__ vp)
{
  gemm_phase(blockIdx.x, threadIdx.x, query, values, Wq, bq, Wv, bv, qp, vp);
}

__global__ __launch_bounds__(512, 4) void k_attn(
    const float* __restrict__ values, const int* __restrict__ mask,
    const float* __restrict__ wc,
    const float* __restrict__ qp, const float* __restrict__ vp,
    float* __restrict__ out_ctx, float* __restrict__ out_w)
{
  __shared__ SM sm;
  const int t = threadIdx.x, lane = t & 63, w = t >> 6;
  const int b = blockIdx.x & 7, qg = blockIdx.x >> 3;
  const int rowbase = b * 128 + qg * 2;
  const int cnt = setup_phase(sm, t, lane, w, b, rowbase, mask, wc, out_w);
  attn_tail(sm, t, lane, w, b, rowbase, cnt, qp, vp, values, out_ctx, out_w);
}

extern "C" void kernel_launch(void* const* d_in, const int* in_sizes, int n_in,
                              void* d_out, int out_size, void* d_ws, size_t ws_size,
                              hipStream_t stream) {
  const float* query  = (const float*)d_in[0];
  const float* values = (const float*)d_in[1];
  const int*   mask   = (const int*)d_in[2];
  const float* Wq     = (const float*)d_in[3];
  const float* bq     = (const float*)d_in[4];
  const float* Wv     = (const float*)d_in[5];
  const float* bv     = (const float*)d_in[6];
  const float* wc     = (const float*)d_in[7];
  // d_in[8] = bc: no effect on outputs (softmax shift-invariance) -> dropped.

  float* out   = (float*)d_out;
  float* out_w = out + (size_t)8 * 128 * 512;
  float* qp    = (float*)d_ws;                 // 1024 x 512
  float* vp    = qp + (size_t)1024 * 512;      // 4096 x 512

  // Deterministic, capture-safe path choice: coop needs all 512 blocks
  // co-resident (2 blocks/CU x 256 CU).
  int nb = 0;
  hipError_t qe = hipOccupancyMaxActiveBlocksPerMultiprocessor(&nb, fused_all, 512, 0);
  bool coop = (qe == hipSuccess && nb >= 2);
  if (coop) {
    void* args[] = {(void*)&query, (void*)&values, (void*)&mask,
                    (void*)&Wq, (void*)&bq, (void*)&Wv, (void*)&bv, (void*)&wc,
                    (void*)&qp, (void*)&vp, (void*)&out, (void*)&out_w};
    if (hipLaunchCooperativeKernel((const void*)fused_all, dim3(512), dim3(512),
                                   args, 0, stream) != hipSuccess)
      coop = false;
  }
  if (!coop) {  // identical math, two dispatches
    k_gemm<<<512, 512, 0, stream>>>(query, values, Wq, bq, Wv, bv, qp, vp);
    k_attn<<<512, 512, 0, stream>>>(values, mask, wc, qp, vp, out, out_w);
  }
}

// Round 8
// 161.281 us; speedup vs baseline: 1.0931x; 1.0931x over previous
//
#include <hip/hip_runtime.h>
#include <hip/hip_bf16.h>
#include <hip/hip_cooperative_groups.h>

namespace cg = cooperative_groups;

// AdditiveAttention: B=8, Q=128, V=512, H=512.
// out = [context (B*Q*H) | weights (B*Q*V)] fp32.
// ws: qp [1024*512] f32 @0, vp [4096*512] f32 @2MB (10MB).
// bc dropped (softmax shift-invariant); sum_h wc[h] const also cancels.
// Score math (verified R1-R7): tanh(y)=1-2r, r=1/(2^(C*y)+1), C=2*log2(e);
//   softmax arg = -C * sum_h wc[h]*r (consts dropped), min-based softmax;
//   shared-exp: e1 = e0 * f_h, f_h = 2^(C*(q1-q0)_h).
// R8 (vs R7): (1) gemm jobs wave-major (i = w*64 + blk-in-XCD) -- R7's
//   block-major map left 12 of 32 CUs/XCD idle while 20 ran 16 serialized
//   jobs; (2) attn score reverted to R5's j-outer form (q/wc via global L1,
//   per-j consts in regs -- R7's slot-outer LDS reads caused 6.8M bank
//   conflicts) plus 2-deep slot prefetch to cover L2 latency.

#define C_SCALE 2.8853900817779268f

typedef __attribute__((ext_vector_type(8))) short short8;
typedef __attribute__((ext_vector_type(4))) float f32x4;

__device__ __forceinline__ float fexp2(float x) { return __builtin_amdgcn_exp2f(x); }
__device__ __forceinline__ float frcp(float x)  { return __builtin_amdgcn_rcpf(x); }
__device__ __forceinline__ float asfloat(unsigned u) { return __builtin_bit_cast(float, u); }
__device__ __forceinline__ unsigned asuint(float f) { return __builtin_bit_cast(unsigned, f); }

// truncation split: hi = x[31:16] as bf16, lo = (x - hi) as bf16
__device__ __forceinline__ void split8(float4 u, float4 v, short8& hi, short8& lo) {
  unsigned a[8] = {asuint(u.x), asuint(u.y), asuint(u.z), asuint(u.w),
                   asuint(v.x), asuint(v.y), asuint(v.z), asuint(v.w)};
  unsigned r[8];
#pragma unroll
  for (int j = 0; j < 8; ++j)
    r[j] = asuint(asfloat(a[j]) - asfloat(a[j] & 0xFFFF0000u));
  uint4 h, l;
  h.x = __builtin_amdgcn_perm(a[1], a[0], 0x07060302u);
  h.y = __builtin_amdgcn_perm(a[3], a[2], 0x07060302u);
  h.z = __builtin_amdgcn_perm(a[5], a[4], 0x07060302u);
  h.w = __builtin_amdgcn_perm(a[7], a[6], 0x07060302u);
  l.x = __builtin_amdgcn_perm(r[1], r[0], 0x07060302u);
  l.y = __builtin_amdgcn_perm(r[3], r[2], 0x07060302u);
  l.z = __builtin_amdgcn_perm(r[5], r[4], 0x07060302u);
  l.w = __builtin_amdgcn_perm(r[7], r[6], 0x07060302u);
  hi = __builtin_bit_cast(short8, h);
  lo = __builtin_bit_cast(short8, l);
}

struct SM {
  int   idxs[512];
  float wls[2][512];     // raw acc per (q, slot); 3.4e38 = invalid
  float wls2[512][2];    // final weights per slot (q0,q1)
  float fls[512];        // f_h = 2^(C*(q1-q0)_h)
  int   cnt8[8];
};

// ---- setup: LDS init, out_w zero, mask compaction; returns cnt -------------
__device__ __forceinline__ int setup_phase(SM& sm, int t, int lane, int w,
    int b, int rowbase, const int* __restrict__ mask, float* __restrict__ out_w)
{
  ((float*)sm.wls)[t]        = 3.4e38f;
  ((float*)sm.wls)[t + 512]  = 3.4e38f;
  ((float*)sm.wls2)[t]       = 0.f;
  ((float*)sm.wls2)[t + 512] = 0.f;
  sm.idxs[t] = 0;
  if (t < 256) {
    float4 z = {0.f, 0.f, 0.f, 0.f};
    ((float4*)(out_w + (size_t)rowbase * 512))[t] = z;
  }
  const int mv = mask[b * 512 + t];
  const unsigned long long bal = __ballot(mv != 0);
  if (lane == 0) sm.cnt8[w] = __popcll(bal);
  __syncthreads();
  int cnt = 0, offw = 0;
#pragma unroll
  for (int j = 0; j < 8; ++j) { if (j == w) offw = cnt; cnt += sm.cnt8[j]; }
  if (mv) {
    int rank = __popcll(bal & ((1ull << lane) - 1ull));
    sm.idxs[offw + rank] = t;
  }
  __syncthreads();
  return cnt;
}

// ---- phase A: per-wave 32x32 split-bf16 MFMA gemm job ----------------------
// WAVE-MAJOR mapping: per XCD r = bx&7, slot i = w*64 + (bx>>3) in [0,512):
//   i < 256: v-job m-tile (r*16 + i>>4), n-tile i&15  (waves 0-3, all blocks)
//   i < 320: q-job m-tile (r*4 + (i-256)>>4), n-tile (i-256)&15  (wave 4)
__device__ __forceinline__ void gemm_phase(int bx, int t,
    const float* __restrict__ query, const float* __restrict__ values,
    const float* __restrict__ Wq, const float* __restrict__ bq,
    const float* __restrict__ Wv, const float* __restrict__ bv,
    float* __restrict__ qp, float* __restrict__ vp)
{
  const int lane = t & 63, w = t >> 6, b = bx & 7;
  const int i = (w << 6) + (bx >> 3);
  if (i >= 320) return;

  int m0; const float *A, *W, *bias; float* outp;
  if (i < 256) {
    m0 = (b * 16 + (i >> 4)) << 5;  A = values; W = Wv; bias = bv; outp = vp;
  } else {
    const int ii = i - 256;
    m0 = (b * 4 + (ii >> 4)) << 5;  A = query;  W = Wq; bias = bq; outp = qp;
  }
  const int n0 = (i & 15) << 5;
  const int frow = lane & 15, fq8 = (lane >> 4) << 3, fquad = lane >> 4;

  const float* ap0 = A + (size_t)(m0 + frow) * 512 + fq8;
  const float* ap1 = ap0 + (size_t)16 * 512;
  const float* wp0 = W + (size_t)(n0 + frow) * 512 + fq8;
  const float* wp1 = wp0 + (size_t)16 * 512;

  f32x4 acc[2][2] = {};
#pragma unroll 1
  for (int kc = 0; kc < 512; kc += 32) {
    float4 c0 = *(const float4*)(ap0 + kc);
    float4 c1 = *(const float4*)(ap0 + kc + 4);
    float4 c2 = *(const float4*)(ap1 + kc);
    float4 c3 = *(const float4*)(ap1 + kc + 4);
    float4 c4 = *(const float4*)(wp0 + kc);
    float4 c5 = *(const float4*)(wp0 + kc + 4);
    float4 c6 = *(const float4*)(wp1 + kc);
    float4 c7 = *(const float4*)(wp1 + kc + 4);
    short8 ahi[2], alo[2], whi[2], wlo[2];
    split8(c0, c1, ahi[0], alo[0]);
    split8(c2, c3, ahi[1], alo[1]);
    split8(c4, c5, whi[0], wlo[0]);
    split8(c6, c7, whi[1], wlo[1]);
#pragma unroll
    for (int mt = 0; mt < 2; ++mt)
#pragma unroll
      for (int nt = 0; nt < 2; ++nt) {
        acc[mt][nt] = __builtin_amdgcn_mfma_f32_16x16x32_bf16(
            alo[mt], whi[nt], acc[mt][nt], 0, 0, 0);
        acc[mt][nt] = __builtin_amdgcn_mfma_f32_16x16x32_bf16(
            ahi[mt], wlo[nt], acc[mt][nt], 0, 0, 0);
        acc[mt][nt] = __builtin_amdgcn_mfma_f32_16x16x32_bf16(
            ahi[mt], whi[nt], acc[mt][nt], 0, 0, 0);
      }
  }

  // epilogue: C/D layout col = lane&15, row = (lane>>4)*4 + reg (R3-verified)
#pragma unroll
  for (int nt = 0; nt < 2; ++nt) {
    const int nn = n0 + nt * 16 + frow;
    const float bn = bias[nn];
#pragma unroll
    for (int mt = 0; mt < 2; ++mt) {
      float vreg[4] = {acc[mt][nt].x, acc[mt][nt].y, acc[mt][nt].z, acc[mt][nt].w};
#pragma unroll
      for (int rr = 0; rr < 4; ++rr) {
        const int m = m0 + mt * 16 + fquad * 4 + rr;
        outp[(size_t)m * 512 + nn] = vreg[rr] + bn;
      }
    }
  }
}

// ---- attn tail: R5 structure (j-outer score) + 2-deep slot prefetch --------
__device__ __forceinline__ void attn_tail(SM& sm, int t, int lane, int w,
    int b, int rowbase, int cnt,
    const float* __restrict__ qp, const float* __restrict__ vp,
    const float* __restrict__ values, const float* __restrict__ wc,
    float* __restrict__ out_ctx, float* __restrict__ out_w)
{
  const float* qr0 = qp + (size_t)rowbase * 512;
  const float* qr1 = qr0 + 512;
  { // stage f_h only; q0/wc read from global (L1) per h-chunk
    sm.fls[t] = fexp2(C_SCALE * (qr1[t] - qr0[t]));
  }
  __syncthreads();

  // score: wave w owns slots [w*4*NSTEP, ...); lane = (g = lane>>4, hquad)
  const int NSTEP = (cnt + 31) >> 5;       // 1..16
  const int sbase = w * (NSTEP << 2);
  const int g  = lane >> 4;
  const int c4 = (lane & 15) << 2;
  const float* vpb = vp + (size_t)b * 512 * 512;

  int   rows[16];
  float a0[16], a1[16];
#pragma unroll
  for (int i = 0; i < 16; ++i) {
    if (i >= NSTEP) break;
    rows[i] = sm.idxs[sbase + (i << 2) + g];
    a0[i] = 0.f; a1[i] = 0.f;
  }

  for (int j = 0; j < 8; ++j) {
    const int hoff = (j << 6) + c4;
    float4 q0v = *(const float4*)(qr0 + hoff);      // global (L1-resident)
    float4 wcv = *(const float4*)(wc + hoff);       // global (L1-resident)
    float4 ffv = *(const float4*)&sm.fls[hoff];     // LDS, conflict-free
    float cq0[4] = {C_SCALE * q0v.x, C_SCALE * q0v.y, C_SCALE * q0v.z, C_SCALE * q0v.w};
    float wc4[4] = {wcv.x, wcv.y, wcv.z, wcv.w};
    float ff4[4] = {ffv.x, ffv.y, ffv.z, ffv.w};

    // 2-deep prefetch pipeline over slot-steps
    float4 vc0 = *(const float4*)(vpb + (size_t)rows[0] * 512 + hoff);
    float4 vc1 = vc0;
    if (NSTEP > 1) vc1 = *(const float4*)(vpb + (size_t)rows[1] * 512 + hoff);
#pragma unroll
    for (int i = 0; i < 16; ++i) {
      if (i >= NSTEP) break;
      float4 vnx = vc0;
      if (i + 2 < NSTEP)
        vnx = *(const float4*)(vpb + (size_t)rows[i + 2] * 512 + hoff);
      float vv[4] = {vc0.x, vc0.y, vc0.z, vc0.w};
#pragma unroll
      for (int k = 0; k < 4; ++k) {
        float e0 = fexp2(__builtin_fmaf(C_SCALE, vv[k], cq0[k]));
        float r0 = frcp(e0 + 1.0f);
        a0[i] = __builtin_fmaf(wc4[k], r0, a0[i]);
        float e1 = e0 * ff4[k];              // shared exp: e1 = e0 * f_h
        float r1 = frcp(e1 + 1.0f);
        a1[i] = __builtin_fmaf(wc4[k], r1, a1[i]);
      }
      vc0 = vc1; vc1 = vnx;
    }
  }

  // per-slot reduce across the 16 lanes sharing g
#pragma unroll
  for (int i = 0; i < 16; ++i) {
    if (i >= NSTEP) break;
    float s0 = a0[i], s1 = a1[i];
#pragma unroll
    for (int off = 1; off < 16; off <<= 1) {
      s0 += __shfl_xor(s0, off, 64);
      s1 += __shfl_xor(s1, off, 64);
    }
    const int s = sbase + (i << 2) + g;
    if ((lane & 15) == i && s < cnt) { sm.wls[0][s] = s0; sm.wls[1][s] = s1; }
  }
  __syncthreads();

  // softmax (min-based; waves 0-3 -> q0, 4-7 -> q1; waves 0/4 write)
  {
    const int mq = (w >= 4) ? 1 : 0;
    const float* sc = sm.wls[mq];
    float4 u0 = ((const float4*)sc)[lane * 2];
    float4 u1 = ((const float4*)sc)[lane * 2 + 1];
    float s8[8] = {u0.x, u0.y, u0.z, u0.w, u1.x, u1.y, u1.z, u1.w};
    float m = s8[0];
#pragma unroll
    for (int k = 1; k < 8; ++k) m = fminf(m, s8[k]);
#pragma unroll
    for (int off = 1; off < 64; off <<= 1) m = fminf(m, __shfl_xor(m, off, 64));
    float e[8], S = 0.f;
#pragma unroll
    for (int k = 0; k < 8; ++k) { e[k] = fexp2(C_SCALE * (m - s8[k])); S += e[k]; }
#pragma unroll
    for (int off = 1; off < 64; off <<= 1) S += __shfl_xor(S, off, 64);
    const float rinv = frcp(S);
    if (w == 0 || w == 4) {
      float* owq = out_w + (size_t)(rowbase + mq) * 512;
#pragma unroll
      for (int k = 0; k < 8; ++k) {
        const int s = lane * 8 + k;
        const float wgt = e[k] * rinv;       // invalid slots -> 0
        sm.wls2[s][mq] = wgt;
        if (s < cnt) owq[sm.idxs[s]] = wgt;
      }
    }
  }
  __syncthreads();

  // context: wave w owns h-window [w*64, w*64+64)
  const int NC = (cnt + 3) >> 2;
  const int hbase = w * 64 + c4;
  const float* vb = values + (size_t)b * 512 * 512;
  float c0[4] = {0.f, 0.f, 0.f, 0.f}, c1[4] = {0.f, 0.f, 0.f, 0.f};
#pragma unroll 4
  for (int i = 0; i < NC; ++i) {
    const int s = (i << 2) + g;
    const int row = sm.idxs[s];
    const float2 wg = *(const float2*)&sm.wls2[s][0];  // padded slots: 0
    const float4 v4 = *(const float4*)(vb + (size_t)row * 512 + hbase);
    float vv[4] = {v4.x, v4.y, v4.z, v4.w};
#pragma unroll
    for (int k = 0; k < 4; ++k) {
      c0[k] = __builtin_fmaf(wg.x, vv[k], c0[k]);
      c1[k] = __builtin_fmaf(wg.y, vv[k], c1[k]);
    }
  }
#pragma unroll
  for (int k = 0; k < 4; ++k) {                        // reduce over g
    c0[k] += __shfl_xor(c0[k], 16, 64); c0[k] += __shfl_xor(c0[k], 32, 64);
    c1[k] += __shfl_xor(c1[k], 16, 64); c1[k] += __shfl_xor(c1[k], 32, 64);
  }
  if (lane < 16) {
    float4 o0 = {c0[0], c0[1], c0[2], c0[3]};
    float4 o1 = {c1[0], c1[1], c1[2], c1[3]};
    *(float4*)(out_ctx + (size_t)rowbase * 512 + w * 64 + lane * 4)       = o0;
    *(float4*)(out_ctx + (size_t)(rowbase + 1) * 512 + w * 64 + lane * 4) = o1;
  }
}

// ---- kernels ---------------------------------------------------------------
__global__ __launch_bounds__(512, 4) void fused_all(
    const float* __restrict__ query, const float* __restrict__ values,
    const int* __restrict__ mask,
    const float* __restrict__ Wq, const float* __restrict__ bq,
    const float* __restrict__ Wv, const float* __restrict__ bv,
    const float* __restrict__ wc,
    float* __restrict__ qp, float* __restrict__ vp,
    float* __restrict__ out_ctx, float* __restrict__ out_w)
{
  __shared__ SM sm;
  const int t = threadIdx.x, lane = t & 63, w = t >> 6;
  const int b = blockIdx.x & 7, qg = blockIdx.x >> 3;
  const int rowbase = b * 128 + qg * 2;
  const int cnt = setup_phase(sm, t, lane, w, b, rowbase, mask, out_w);
  gemm_phase(blockIdx.x, t, query, values, Wq, bq, Wv, bv, qp, vp);
  cg::this_grid().sync();
  attn_tail(sm, t, lane, w, b, rowbase, cnt, qp, vp, values, wc, out_ctx, out_w);
}

__global__ __launch_bounds__(512, 4) void k_gemm(
    const float* __restrict__ query, const float* __restrict__ values,
    const float* __restrict__ Wq, const float* __restrict__ bq,
    const float* __restrict__ Wv, const float* __restrict__ bv,
    float* __restrict__ qp, float* __restrict__ vp)
{
  gemm_phase(blockIdx.x, threadIdx.x, query, values, Wq, bq, Wv, bv, qp, vp);
}

__global__ __launch_bounds__(512, 4) void k_attn(
    const float* __restrict__ values, const int* __restrict__ mask,
    const float* __restrict__ wc,
    const float* __restrict__ qp, const float* __restrict__ vp,
    float* __restrict__ out_ctx, float* __restrict__ out_w)
{
  __shared__ SM sm;
  const int t = threadIdx.x, lane = t & 63, w = t >> 6;
  const int b = blockIdx.x & 7, qg = blockIdx.x >> 3;
  const int rowbase = b * 128 + qg * 2;
  const int cnt = setup_phase(sm, t, lane, w, b, rowbase, mask, out_w);
  attn_tail(sm, t, lane, w, b, rowbase, cnt, qp, vp, values, wc, out_ctx, out_w);
}

extern "C" void kernel_launch(void* const* d_in, const int* in_sizes, int n_in,
                              void* d_out, int out_size, void* d_ws, size_t ws_size,
                              hipStream_t stream) {
  const float* query  = (const float*)d_in[0];
  const float* values = (const float*)d_in[1];
  const int*   mask   = (const int*)d_in[2];
  const float* Wq     = (const float*)d_in[3];
  const float* bq     = (const float*)d_in[4];
  const float* Wv     = (const float*)d_in[5];
  const float* bv     = (const float*)d_in[6];
  const float* wc     = (const float*)d_in[7];
  // d_in[8] = bc: no effect on outputs (softmax shift-invariance) -> dropped.

  float* out   = (float*)d_out;
  float* out_w = out + (size_t)8 * 128 * 512;
  float* qp    = (float*)d_ws;                 // 1024 x 512
  float* vp    = qp + (size_t)1024 * 512;      // 4096 x 512

  int nb = 0;
  hipError_t qe = hipOccupancyMaxActiveBlocksPerMultiprocessor(&nb, fused_all, 512, 0);
  bool coop = (qe == hipSuccess && nb >= 2);
  if (coop) {
    void* args[] = {(void*)&query, (void*)&values, (void*)&mask,
                    (void*)&Wq, (void*)&bq, (void*)&Wv, (void*)&bv, (void*)&wc,
                    (void*)&qp, (void*)&vp, (void*)&out, (void*)&out_w};
    if (hipLaunchCooperativeKernel((const void*)fused_all, dim3(512), dim3(512),
                                   args, 0, stream) != hipSuccess)
      coop = false;
  }
  if (!coop) {  // identical math, two dispatches
    k_gemm<<<512, 512, 0, stream>>>(query, values, Wq, bq, Wv, bv, qp, vp);
    k_attn<<<512, 512, 0, stream>>>(values, mask, wc, qp, vp, out, out_w);
  }
}